// Round 6
// baseline (1613.884 us; speedup 1.0000x reference)
//
#include <hip/hip_runtime.h>

// LSTMClassifier: B=2048, T=500, H1=128, H2=64, D_IN=1, FC 64->128->4.
//
// Round 6 = Round 5 structure + WEIGHTS PINNED INTO AGPRs.
// Evidence R3-R5: VGPR_Count pinned at 128 for 512-thread blocks under
// launch_bounds(512,2)/(512,1)/waves_per_eu(2,2); WRITE_SIZE 27-30 MB =
// ~90 regs/lane spilled to scratch and reloaded through L1/L2 every step
// (~3000 cyc/step). The allocator never uses the AGPR half of the unified
// register file for spill relief. Fix: pin every weight fragment into the
// AGPR class via empty inline-asm "+a" constraints. gfx950 MFMA reads B
// directly from AGPRs (cdna4_isa.md #10) -> zero per-use copies, VGPR
// demand drops to ~95/wave < 128 -> no scratch.
//
// Structure (unchanged from R3/R5):
//  - Skewed pipeline, 1 barrier/step: iter i, waves 4-7 compute h1(i)
//    (32 LSTM1 units each, 32 MFMA, 4 cells/lane), waves 0-3 compute h2(i-1)
//    (16 LSTM2 units, 24 MFMA, 2 cells/lane). Parity: LSTM2 reads h1b[prv],
//    h2b[cur], writes h2b[prv] -- race-free.
//  - Weight frags aliased in one Wreg[8][4] (no wave needs both sets).
//  - log2e pre-folded into weights/biases -> bare v_exp_f32; cell merged
//    under common denominators: 5 exp2 + 2 rcp per cell, exact algebra.
//  - s_setprio(1) around MFMA clusters (role-split waves share a SIMD).

#define B_   2048
#define T_   500
#define BM   8
#define NBLK (B_ / BM)   // 256 blocks = 1 per CU

typedef __attribute__((ext_vector_type(8))) short bf16x8;   // 8 bf16 = 4 VGPR
typedef __attribute__((ext_vector_type(4))) float f32x4;

#define LOG2E 1.44269504088896340736f

// Pin a 128-bit fragment's live range into the AGPR register class.
#define PIN_A(x) asm volatile("" : "+a"(x))

static __device__ __forceinline__ short f2bf(float f) {
  unsigned u = __builtin_bit_cast(unsigned, f);
  u = (u + 0x7fffu + ((u >> 16) & 1u)) >> 16;   // RNE
  return (short)u;
}

// Gates pre-scaled by log2e. c' = sigm(f)c + sigm(i)tanh(g); h = sigm(o)tanh(c').
// sigm(a)tanh(b) = (Eg-1)/((1+Ei)(1+Eg)); merged c-update under one rcp.
// 5 exp2 + 2 rcp = 7 transcendentals, exact algebra.
static __device__ __forceinline__ float lstm_cell_s(float gi, float gf, float gg,
                                                    float go, float& c) {
  float Ei = __builtin_amdgcn_exp2f(-gi);
  float Eg = __builtin_amdgcn_exp2f(gg + gg);
  float Ef = __builtin_amdgcn_exp2f(-gf);
  float Eo = __builtin_amdgcn_exp2f(-go);
  float t12 = (1.f + Ei) * (1.f + Eg);
  float num = c * t12 + (Eg - 1.f) * (1.f + Ef);
  c = num * __builtin_amdgcn_rcpf((1.f + Ef) * t12);
  float Ec = __builtin_amdgcn_exp2f(2.88539008177792681472f * c);  // 2*log2e*c
  return (Ec - 1.f) * __builtin_amdgcn_rcpf((1.f + Eo) * (1.f + Ec));
}

__global__
__attribute__((amdgpu_flat_work_group_size(512, 512), amdgpu_waves_per_eu(2, 2)))
void lstm_fused(const float* __restrict__ X,     // (B,1,T)
                const float* __restrict__ Wp,    // (128,1)
                const float* __restrict__ bp,    // (128)
                const float* __restrict__ Wih1,  // (512,128)
                const float* __restrict__ Whh1,  // (512,128)
                const float* __restrict__ bih1,  // (512)
                const float* __restrict__ bhh1,  // (512)
                const float* __restrict__ Wih2,  // (256,128)
                const float* __restrict__ Whh2,  // (256,64)
                const float* __restrict__ bih2,  // (256)
                const float* __restrict__ bhh2,  // (256)
                const float* __restrict__ W1,    // (128,64)
                const float* __restrict__ b1,    // (128)
                const float* __restrict__ W2,    // (4,128)
                const float* __restrict__ b2,    // (4)
                float* __restrict__ Out) {       // (B,4)
  __shared__ __align__(16) short h1b[2][16][136];  // h1 bf16 dbuf (rows 8..15 stay 0)
  __shared__ __align__(16) short h2b[2][16][72];   // h2 bf16 dbuf
  __shared__ float h2f[8][64];       // final h2 fp32 for FC head
  __shared__ float fc1s[8][132];     // fc1 activations (+4 pad)

  const int tid = threadIdx.x;
  const int ln = tid & 63;
  const int wv = tid >> 6;     // wave 0..7;  0-3 = LSTM2, 4-7 = LSTM1
  const int cl = ln & 15;      // fragment column / A-row
  const int kg = ln >> 4;      // K-group 0..3
  const int r0 = blockIdx.x * BM;
  const bool isL1 = (wv >= 4);
  const int w1 = wv - 4;       // LSTM1 wave index 0..3

  // Weight fragments -- ALIASED between roles, PINNED to AGPRs.
  // LSTM1 (wv>=4): Wreg[g*4+n][0..3] = Whh1 frags, units 32*w1+16g+cl, gate n.
  // LSTM2 (wv<4):  Wreg[n][0..3] = Wih2 frags; Wreg[4+n][0..1] = Whh2 frags.
  bf16x8 Wreg[8][4];
  float uv[16];   // LSTM1: uv[0..7]=u1*log2e, uv[8..15]=v1*log2e. LSTM2: uv[0..3]=bias*log2e.

  // ---------------- one-time setup (weights pre-scaled by log2e) ----------
  if (isL1) {
#pragma unroll
    for (int g = 0; g < 2; ++g) {
#pragma unroll
      for (int n = 0; n < 4; ++n) {
        const int R = n * 128 + 32 * w1 + 16 * g + cl;
        float u = 0.f, vv = bih1[R] + bhh1[R];
        const float4* Wi4 = (const float4*)(Wih1 + R * 128);
        const float4* Wp4 = (const float4*)Wp;
        const float4* bp4 = (const float4*)bp;
#pragma unroll 4
        for (int d = 0; d < 32; ++d) {
          float4 a = Wi4[d], pw = Wp4[d], qb = bp4[d];
          u  += a.x*pw.x + a.y*pw.y + a.z*pw.z + a.w*pw.w;
          vv += a.x*qb.x + a.y*qb.y + a.z*qb.z + a.w*qb.w;
        }
        uv[g * 4 + n] = u * LOG2E;
        uv[8 + g * 4 + n] = vv * LOG2E;
#pragma unroll
        for (int kf = 0; kf < 4; ++kf) {
          const float4* s4 = (const float4*)(Whh1 + R * 128 + kf * 32 + kg * 8);
          float4 a0 = s4[0], a1 = s4[1];
          bf16x8 fr;
          fr[0]=f2bf(a0.x*LOG2E); fr[1]=f2bf(a0.y*LOG2E);
          fr[2]=f2bf(a0.z*LOG2E); fr[3]=f2bf(a0.w*LOG2E);
          fr[4]=f2bf(a1.x*LOG2E); fr[5]=f2bf(a1.y*LOG2E);
          fr[6]=f2bf(a1.z*LOG2E); fr[7]=f2bf(a1.w*LOG2E);
          Wreg[g * 4 + n][kf] = fr;
          PIN_A(Wreg[g * 4 + n][kf]);
        }
      }
    }
  } else {
#pragma unroll
    for (int n = 0; n < 4; ++n) {
      const int R = n * 64 + 16 * wv + cl;
      uv[n] = (bih2[R] + bhh2[R]) * LOG2E;
#pragma unroll
      for (int kf = 0; kf < 4; ++kf) {
        const float4* s4 = (const float4*)(Wih2 + R * 128 + kf * 32 + kg * 8);
        float4 a0 = s4[0], a1 = s4[1];
        bf16x8 fr;
        fr[0]=f2bf(a0.x*LOG2E); fr[1]=f2bf(a0.y*LOG2E);
        fr[2]=f2bf(a0.z*LOG2E); fr[3]=f2bf(a0.w*LOG2E);
        fr[4]=f2bf(a1.x*LOG2E); fr[5]=f2bf(a1.y*LOG2E);
        fr[6]=f2bf(a1.z*LOG2E); fr[7]=f2bf(a1.w*LOG2E);
        Wreg[n][kf] = fr;
        PIN_A(Wreg[n][kf]);
      }
#pragma unroll
      for (int kf = 0; kf < 2; ++kf) {
        const float4* s4 = (const float4*)(Whh2 + R * 64 + kf * 32 + kg * 8);
        float4 a0 = s4[0], a1 = s4[1];
        bf16x8 fr;
        fr[0]=f2bf(a0.x*LOG2E); fr[1]=f2bf(a0.y*LOG2E);
        fr[2]=f2bf(a0.z*LOG2E); fr[3]=f2bf(a0.w*LOG2E);
        fr[4]=f2bf(a1.x*LOG2E); fr[5]=f2bf(a1.y*LOG2E);
        fr[6]=f2bf(a1.z*LOG2E); fr[7]=f2bf(a1.w*LOG2E);
        Wreg[4 + n][kf] = fr;
        PIN_A(Wreg[4 + n][kf]);
      }
    }
  }

  // zero both h-state buffers (rows 8..15 must stay zero forever)
  for (int i = tid; i < 2 * 16 * 136; i += 512) ((short*)h1b)[i] = 0;
  for (int i = tid; i < 2 * 16 * 72;  i += 512) ((short*)h2b)[i] = 0;
  __syncthreads();

  // per-lane persistent state.
  // LSTM1 wave: 4 cells/lane -> (g0,rA)=cA (g0,rB)=cA2 (g1,rA)=cB (g1,rB)=cB2.
  // LSTM2 wave: 2 cells/lane -> cA2 (rA), cB2 (rB).
  float cA = 0.f, cB = 0.f, cA2 = 0.f, cB2 = 0.f;
  const int rA = (kg < 2) ? kg * 4 : (kg - 2) * 4 + 2;   // redistributed rows
  const int rB = rA + 1;

  float xr[4];
#pragma unroll
  for (int e = 0; e < 4; ++e)
    xr[e] = (isL1 && kg < 2) ? X[(size_t)(r0 + kg * 4 + e) * T_ + 0] : 0.f;

  // ---------------- the scan: iter i -> h1(i) [waves 4-7] + h2(i-1) [0-3] --
  for (int i = 0; i <= T_; ++i) {
    const int cur = i & 1, prv = cur ^ 1;

    if (isL1) {
      if (i < T_) {
        bf16x8 a1[4];
#pragma unroll
        for (int kf = 0; kf < 4; ++kf)
          a1[kf] = *(const bf16x8*)&h1b[prv][cl][kf * 32 + kg * 8];

        f32x4 acc[2][4];
#pragma unroll
        for (int g = 0; g < 2; ++g)
#pragma unroll
          for (int n = 0; n < 4; ++n) {
            f32x4 a;
#pragma unroll
            for (int e = 0; e < 4; ++e)
              a[e] = xr[e] * uv[g * 4 + n] + uv[8 + g * 4 + n];
            acc[g][n] = a;
          }
        __builtin_amdgcn_s_setprio(1);
#pragma unroll
        for (int g = 0; g < 2; ++g)
#pragma unroll
          for (int n = 0; n < 4; ++n)
#pragma unroll
            for (int kf = 0; kf < 4; ++kf)
              acc[g][n] = __builtin_amdgcn_mfma_f32_16x16x32_bf16(
                  a1[kf], Wreg[g * 4 + n][kf], acc[g][n], 0, 0, 0);
        __builtin_amdgcn_s_setprio(0);

        // prefetch x for next step (clamped; rows valid only for kg<2)
        if (kg < 2) {
          const int tn = (i + 1 < T_) ? i + 1 : T_ - 1;
#pragma unroll
          for (int e = 0; e < 4; ++e)
            xr[e] = X[(size_t)(r0 + kg * 4 + e) * T_ + tn];
        }

#pragma unroll
        for (int g = 0; g < 2; ++g) {
          float gA[4], gB[4];
#pragma unroll
          for (int n = 0; n < 4; ++n) {
            float s2 = __shfl_xor(acc[g][n][2], 32);
            float s3 = __shfl_xor(acc[g][n][3], 32);
            gA[n] = (kg < 2) ? acc[g][n][0] : s2;
            gB[n] = (kg < 2) ? acc[g][n][1] : s3;
          }
          float crA = (g == 0) ? cA : cB;
          float crB = (g == 0) ? cA2 : cB2;
          float hA = lstm_cell_s(gA[0], gA[1], gA[2], gA[3], crA);
          float hB = lstm_cell_s(gB[0], gB[1], gB[2], gB[3], crB);
          if (g == 0) { cA = crA; cA2 = crB; } else { cB = crA; cB2 = crB; }

          const int uu = 32 * w1 + 16 * g + cl;
          h1b[cur][rA][uu] = f2bf(hA);
          h1b[cur][rB][uu] = f2bf(hB);
        }
      }
    } else {
      if (i > 0) {
        bf16x8 ah[4], ag[2];
#pragma unroll
        for (int kf = 0; kf < 4; ++kf)
          ah[kf] = *(const bf16x8*)&h1b[prv][cl][kf * 32 + kg * 8];
#pragma unroll
        for (int kf = 0; kf < 2; ++kf)
          ag[kf] = *(const bf16x8*)&h2b[cur][cl][kf * 32 + kg * 8];

        f32x4 acc2[4];
#pragma unroll
        for (int n = 0; n < 4; ++n)
          acc2[n] = (f32x4){uv[n], uv[n], uv[n], uv[n]};
        __builtin_amdgcn_s_setprio(1);
#pragma unroll
        for (int n = 0; n < 4; ++n) {
#pragma unroll
          for (int kf = 0; kf < 2; ++kf)
            acc2[n] = __builtin_amdgcn_mfma_f32_16x16x32_bf16(
                ag[kf], Wreg[4 + n][kf], acc2[n], 0, 0, 0);
#pragma unroll
          for (int kf = 0; kf < 4; ++kf)
            acc2[n] = __builtin_amdgcn_mfma_f32_16x16x32_bf16(
                ah[kf], Wreg[n][kf], acc2[n], 0, 0, 0);
        }
        __builtin_amdgcn_s_setprio(0);

        float gA[4], gB[4];
#pragma unroll
        for (int n = 0; n < 4; ++n) {
          float s2 = __shfl_xor(acc2[n][2], 32);
          float s3 = __shfl_xor(acc2[n][3], 32);
          gA[n] = (kg < 2) ? acc2[n][0] : s2;
          gB[n] = (kg < 2) ? acc2[n][1] : s3;
        }
        float hA = lstm_cell_s(gA[0], gA[1], gA[2], gA[3], cA2);
        float hB = lstm_cell_s(gB[0], gB[1], gB[2], gB[3], cB2);
        const int uu = 16 * wv + cl;
        h2b[prv][rA][uu] = f2bf(hA);   // h2(i-1) lives at parity (i-1)&1 = prv
        h2b[prv][rB][uu] = f2bf(hB);
        if (i == T_) { h2f[rA][uu] = hA; h2f[rB][uu] = hB; }
      }
    }
    __syncthreads();   // publish h1(i) and h2(i-1)
  }

  // ---------------- FC head (fp32) ----------------
  // fc1: (8 x 64) @ (64 x 128) + b1, relu
  {
    const int u = tid & 127, r2 = tid >> 7;   // r2 0..3 -> rows 2r2, 2r2+1
    float a0 = b1[u], a1f = b1[u];
    for (int k = 0; k < 64; ++k) {
      float w = W1[u * 64 + k];
      a0  += h2f[r2 * 2 + 0][k] * w;
      a1f += h2f[r2 * 2 + 1][k] * w;
    }
    fc1s[r2 * 2 + 0][u] = fmaxf(a0, 0.f);
    fc1s[r2 * 2 + 1][u] = fmaxf(a1f, 0.f);
  }
  __syncthreads();
  // fc2: (8 x 128) @ (128 x 4) + b2
  if (tid < 32) {
    const int r = tid >> 2, cls = tid & 3;
    float a = b2[cls];
    for (int k = 0; k < 128; ++k) a += fc1s[r][k] * W2[cls * 128 + k];
    Out[(size_t)(r0 + r) * 4 + cls] = a;
  }
}

extern "C" void kernel_launch(void* const* d_in, const int* in_sizes, int n_in,
                              void* d_out, int out_size, void* d_ws, size_t ws_size,
                              hipStream_t stream) {
  const float* X    = (const float*)d_in[0];
  const float* Wp   = (const float*)d_in[1];
  const float* bp   = (const float*)d_in[2];
  const float* Wih1 = (const float*)d_in[3];
  const float* Whh1 = (const float*)d_in[4];
  const float* bih1 = (const float*)d_in[5];
  const float* bhh1 = (const float*)d_in[6];
  const float* Wih2 = (const float*)d_in[7];
  const float* Whh2 = (const float*)d_in[8];
  const float* bih2 = (const float*)d_in[9];
  const float* bhh2 = (const float*)d_in[10];
  const float* W1   = (const float*)d_in[11];
  const float* b1   = (const float*)d_in[12];
  const float* W2   = (const float*)d_in[13];
  const float* b2   = (const float*)d_in[14];
  float* Out = (float*)d_out;

  hipLaunchKernelGGL(lstm_fused, dim3(NBLK), dim3(512), 0, stream,
                     X, Wp, bp, Wih1, Whh1, bih1, bhh1,
                     Wih2, Whh2, bih2, bhh2, W1, b1, W2, b2, Out);
}

// Round 7
// 534.751 us; speedup vs baseline: 3.0180x; 3.0180x over previous
//
#include <hip/hip_runtime.h>

// LSTMClassifier: B=2048, T=500, H1=128, H2=64, D_IN=1, FC 64->128->4.
//
// Round 7: DESIGN FOR 128 ARCH-VGPRs (stop fighting the allocator).
// Evidence R1-R6: 512-thread blocks get arch-VGPR budget 128 no matter what
// (launch_bounds / waves_per_eu / AGPR pins all ineffective); register
// liveness unions across the if(isL1) branches, so R3-R6's Wreg[8][4]
// (128 VGPR) + role-specific extras = ~190 static demand -> ~50-90 reg
// scratch spill reloaded every step (WRITE_SIZE 23-30 MB, ~3000 cyc/step).
//
// New structure:
//  - 768 threads = 12 waves: waves 4..11 = LSTM1 (16 units each, frag=gate,
//    Whh1 slice = 16 frags = 64 VGPR -- R2's proven-fitting shape);
//    waves 0..3 = LSTM2 (16 units each, frag=gate, Wih2 16 frags in the
//    SAME Wreg[4][4] slots as L1's Whh1 -> union stays 64 VGPR).
//  - Whh2 fragments in LDS, conflict-free layout [wv][n][kf][lane]*16B
//    (lane-consecutive -> 2-way bank alias = free), -32 VGPR on L2 waves.
//  - Static per-wave demand ~ 64(Wreg) + 8(uv) + 16(a1) + 16(acc,likely
//    AGPR) + 8(ag) + misc ~= 124-140 -> fits 128-168 budget, no hot spill.
//  - Skewed pipeline, 1 barrier/step (R5 parity scheme, numerically proven):
//    iter i: L1 waves compute h1(i) (16 MFMA, 2 cells/lane), L2 waves
//    compute h2(i-1) (24 MFMA, 2 cells/lane).
//  - 7-trans cell (5 exp2 + 2 rcp, log2e pre-folded), setprio around MFMA.

#define B_   2048
#define T_   500
#define BM   8
#define NBLK (B_ / BM)   // 256 blocks = 1 per CU
#define NTHR 768         // 12 waves

typedef __attribute__((ext_vector_type(8))) short bf16x8;   // 8 bf16 = 4 VGPR
typedef __attribute__((ext_vector_type(4))) float f32x4;

#define LOG2E 1.44269504088896340736f

static __device__ __forceinline__ short f2bf(float f) {
  unsigned u = __builtin_bit_cast(unsigned, f);
  u = (u + 0x7fffu + ((u >> 16) & 1u)) >> 16;   // RNE
  return (short)u;
}

// Gates pre-scaled by log2e. c' = sigm(f)c + sigm(i)tanh(g); h = sigm(o)tanh(c').
// 5 exp2 + 2 rcp = 7 transcendentals, exact algebra.
static __device__ __forceinline__ float lstm_cell_s(float gi, float gf, float gg,
                                                    float go, float& c) {
  float Ei = __builtin_amdgcn_exp2f(-gi);
  float Eg = __builtin_amdgcn_exp2f(gg + gg);
  float Ef = __builtin_amdgcn_exp2f(-gf);
  float Eo = __builtin_amdgcn_exp2f(-go);
  float t12 = (1.f + Ei) * (1.f + Eg);
  float num = c * t12 + (Eg - 1.f) * (1.f + Ef);
  c = num * __builtin_amdgcn_rcpf((1.f + Ef) * t12);
  float Ec = __builtin_amdgcn_exp2f(2.88539008177792681472f * c);  // 2*log2e*c
  return (Ec - 1.f) * __builtin_amdgcn_rcpf((1.f + Eo) * (1.f + Ec));
}

__global__ __launch_bounds__(NTHR)
void lstm_fused(const float* __restrict__ X,     // (B,1,T)
                const float* __restrict__ Wp,    // (128,1)
                const float* __restrict__ bp,    // (128)
                const float* __restrict__ Wih1,  // (512,128)
                const float* __restrict__ Whh1,  // (512,128)
                const float* __restrict__ bih1,  // (512)
                const float* __restrict__ bhh1,  // (512)
                const float* __restrict__ Wih2,  // (256,128)
                const float* __restrict__ Whh2,  // (256,64)
                const float* __restrict__ bih2,  // (256)
                const float* __restrict__ bhh2,  // (256)
                const float* __restrict__ W1,    // (128,64)
                const float* __restrict__ b1,    // (128)
                const float* __restrict__ W2,    // (4,128)
                const float* __restrict__ b2,    // (4)
                float* __restrict__ Out) {       // (B,4)
  __shared__ __align__(16) short h1b[2][16][136];    // 8704 B (rows 8..15 stay 0)
  __shared__ __align__(16) short h2b[2][16][72];     // 4608 B
  __shared__ __align__(16) short w2h[4][4][2][64][8];// 32768 B: Whh2 frags
  __shared__ float h2f[8][64];                       // 2048 B
  __shared__ float fc1s[8][132];                     // 4224 B  (total ~52.4 KB)

  const int tid = threadIdx.x;
  const int ln = tid & 63;
  const int wv = tid >> 6;     // wave 0..11; 0-3 = LSTM2, 4-11 = LSTM1
  const int cl = ln & 15;      // fragment column (unit within slice)
  const int kg = ln >> 4;      // K-group 0..3
  const int r0 = blockIdx.x * BM;
  const bool isL1 = (wv >= 4);
  const int w1 = wv - 4;       // LSTM1 wave index 0..7

  // Weight fragments -- SAME slots for both roles (union stays 64 VGPR).
  // L1 (wv>=4): Wreg[n][kf] = Whh1 frag, gate n, units 16*w1..+16.
  // L2 (wv<4):  Wreg[n][kf] = Wih2 frag, gate n, units 16*wv..+16.
  bf16x8 Wreg[4][4];
  float uv[8];  // L1: uv[0..3]=u1*log2e, uv[4..7]=v1*log2e. L2: uv[0..3]=bias*log2e.

  // ---------------- one-time setup (weights pre-scaled by log2e) ----------
  if (isL1) {
#pragma unroll
    for (int n = 0; n < 4; ++n) {
      const int R = n * 128 + 16 * w1 + cl;
      float u = 0.f, vv = bih1[R] + bhh1[R];
      const float4* Wi4 = (const float4*)(Wih1 + R * 128);
      const float4* Wp4 = (const float4*)Wp;
      const float4* bp4 = (const float4*)bp;
#pragma unroll 4
      for (int d = 0; d < 32; ++d) {
        float4 a = Wi4[d], pw = Wp4[d], qb = bp4[d];
        u  += a.x*pw.x + a.y*pw.y + a.z*pw.z + a.w*pw.w;
        vv += a.x*qb.x + a.y*qb.y + a.z*qb.z + a.w*qb.w;
      }
      uv[n] = u * LOG2E;
      uv[4 + n] = vv * LOG2E;
#pragma unroll
      for (int kf = 0; kf < 4; ++kf) {
        const float4* s4 = (const float4*)(Whh1 + R * 128 + kf * 32 + kg * 8);
        float4 a0 = s4[0], a1 = s4[1];
        bf16x8 fr;
        fr[0]=f2bf(a0.x*LOG2E); fr[1]=f2bf(a0.y*LOG2E);
        fr[2]=f2bf(a0.z*LOG2E); fr[3]=f2bf(a0.w*LOG2E);
        fr[4]=f2bf(a1.x*LOG2E); fr[5]=f2bf(a1.y*LOG2E);
        fr[6]=f2bf(a1.z*LOG2E); fr[7]=f2bf(a1.w*LOG2E);
        Wreg[n][kf] = fr;
      }
    }
  } else {
#pragma unroll
    for (int n = 0; n < 4; ++n) {
      const int R = n * 64 + 16 * wv + cl;
      uv[n] = (bih2[R] + bhh2[R]) * LOG2E;
#pragma unroll
      for (int kf = 0; kf < 4; ++kf) {
        const float4* s4 = (const float4*)(Wih2 + R * 128 + kf * 32 + kg * 8);
        float4 a0 = s4[0], a1 = s4[1];
        bf16x8 fr;
        fr[0]=f2bf(a0.x*LOG2E); fr[1]=f2bf(a0.y*LOG2E);
        fr[2]=f2bf(a0.z*LOG2E); fr[3]=f2bf(a0.w*LOG2E);
        fr[4]=f2bf(a1.x*LOG2E); fr[5]=f2bf(a1.y*LOG2E);
        fr[6]=f2bf(a1.z*LOG2E); fr[7]=f2bf(a1.w*LOG2E);
        Wreg[n][kf] = fr;
      }
      // Whh2 B-frags -> LDS (conflict-free: lane-consecutive 16B slots)
#pragma unroll
      for (int kf = 0; kf < 2; ++kf) {
        const float4* s4 = (const float4*)(Whh2 + R * 64 + kf * 32 + kg * 8);
        float4 a0 = s4[0], a1 = s4[1];
        short* dst = &w2h[wv][n][kf][ln][0];
        dst[0]=f2bf(a0.x*LOG2E); dst[1]=f2bf(a0.y*LOG2E);
        dst[2]=f2bf(a0.z*LOG2E); dst[3]=f2bf(a0.w*LOG2E);
        dst[4]=f2bf(a1.x*LOG2E); dst[5]=f2bf(a1.y*LOG2E);
        dst[6]=f2bf(a1.z*LOG2E); dst[7]=f2bf(a1.w*LOG2E);
      }
    }
  }

  // zero both h-state buffers (rows 8..15 must stay zero forever)
  for (int i = tid; i < 2 * 16 * 136; i += NTHR) ((short*)h1b)[i] = 0;
  for (int i = tid; i < 2 * 16 * 72;  i += NTHR) ((short*)h2b)[i] = 0;
  __syncthreads();

  // per-lane persistent state: every wave has exactly 2 cells (rA, rB).
  float c0 = 0.f, c1 = 0.f;
  const int rA = (kg < 2) ? kg * 4 : (kg - 2) * 4 + 2;   // redistributed rows
  const int rB = rA + 1;
  const int uu = 16 * (isL1 ? w1 : wv) + cl;             // owned unit

  float xr[4];   // x for rows kg*4+e (valid for L1, kg<2)
#pragma unroll
  for (int e = 0; e < 4; ++e)
    xr[e] = (isL1 && kg < 2) ? X[(size_t)(r0 + kg * 4 + e) * T_ + 0] : 0.f;

  // ---------------- the scan: iter i -> h1(i) [L1 waves] + h2(i-1) [L2] ---
  for (int i = 0; i <= T_; ++i) {
    const int cur = i & 1, prv = cur ^ 1;

    if (isL1) {
      if (i < T_) {
        bf16x8 a1[4];
#pragma unroll
        for (int kf = 0; kf < 4; ++kf)
          a1[kf] = *(const bf16x8*)&h1b[prv][cl][kf * 32 + kg * 8];

        f32x4 acc[4];
#pragma unroll
        for (int n = 0; n < 4; ++n) {
#pragma unroll
          for (int e = 0; e < 4; ++e)
            acc[n][e] = xr[e] * uv[n] + uv[4 + n];
        }
        __builtin_amdgcn_s_setprio(1);
#pragma unroll
        for (int n = 0; n < 4; ++n)
#pragma unroll
          for (int kf = 0; kf < 4; ++kf)
            acc[n] = __builtin_amdgcn_mfma_f32_16x16x32_bf16(
                a1[kf], Wreg[n][kf], acc[n], 0, 0, 0);
        __builtin_amdgcn_s_setprio(0);

        // prefetch x for next step (clamped; rows valid only for kg<2)
        if (kg < 2) {
          const int tn = (i + 1 < T_) ? i + 1 : T_ - 1;
#pragma unroll
          for (int e = 0; e < 4; ++e)
            xr[e] = X[(size_t)(r0 + kg * 4 + e) * T_ + tn];
        }

        float gA[4], gB[4];
#pragma unroll
        for (int n = 0; n < 4; ++n) {
          float s2 = __shfl_xor(acc[n][2], 32);
          float s3 = __shfl_xor(acc[n][3], 32);
          gA[n] = (kg < 2) ? acc[n][0] : s2;
          gB[n] = (kg < 2) ? acc[n][1] : s3;
        }
        float hA = lstm_cell_s(gA[0], gA[1], gA[2], gA[3], c0);
        float hB = lstm_cell_s(gB[0], gB[1], gB[2], gB[3], c1);
        h1b[cur][rA][uu] = f2bf(hA);
        h1b[cur][rB][uu] = f2bf(hB);
      }
    } else {
      if (i > 0) {
        bf16x8 a1[4], ag[2];
#pragma unroll
        for (int kf = 0; kf < 4; ++kf)
          a1[kf] = *(const bf16x8*)&h1b[prv][cl][kf * 32 + kg * 8];
#pragma unroll
        for (int kf = 0; kf < 2; ++kf)
          ag[kf] = *(const bf16x8*)&h2b[cur][cl][kf * 32 + kg * 8];

        f32x4 acc[4];
#pragma unroll
        for (int n = 0; n < 4; ++n)
          acc[n] = (f32x4){uv[n], uv[n], uv[n], uv[n]};
        __builtin_amdgcn_s_setprio(1);
#pragma unroll
        for (int n = 0; n < 4; ++n) {
          bf16x8 w0 = *(const bf16x8*)&w2h[wv][n][0][ln][0];
          bf16x8 w1f = *(const bf16x8*)&w2h[wv][n][1][ln][0];
          acc[n] = __builtin_amdgcn_mfma_f32_16x16x32_bf16(ag[0], w0, acc[n], 0, 0, 0);
          acc[n] = __builtin_amdgcn_mfma_f32_16x16x32_bf16(ag[1], w1f, acc[n], 0, 0, 0);
#pragma unroll
          for (int kf = 0; kf < 4; ++kf)
            acc[n] = __builtin_amdgcn_mfma_f32_16x16x32_bf16(
                a1[kf], Wreg[n][kf], acc[n], 0, 0, 0);
        }
        __builtin_amdgcn_s_setprio(0);

        float gA[4], gB[4];
#pragma unroll
        for (int n = 0; n < 4; ++n) {
          float s2 = __shfl_xor(acc[n][2], 32);
          float s3 = __shfl_xor(acc[n][3], 32);
          gA[n] = (kg < 2) ? acc[n][0] : s2;
          gB[n] = (kg < 2) ? acc[n][1] : s3;
        }
        float hA = lstm_cell_s(gA[0], gA[1], gA[2], gA[3], c0);
        float hB = lstm_cell_s(gB[0], gB[1], gB[2], gB[3], c1);
        h2b[prv][rA][uu] = f2bf(hA);   // h2(i-1) lives at parity (i-1)&1 = prv
        h2b[prv][rB][uu] = f2bf(hB);
        if (i == T_) { h2f[rA][uu] = hA; h2f[rB][uu] = hB; }
      }
    }
    __syncthreads();   // publish h1(i) and h2(i-1)
  }

  // ---------------- FC head (fp32) ----------------
  // fc1: (8 x 64) @ (64 x 128) + b1, relu   (threads 0..511 only)
  if (tid < 512) {
    const int u = tid & 127, r2 = tid >> 7;   // r2 0..3 -> rows 2r2, 2r2+1
    float a0 = b1[u], a1f = b1[u];
    for (int k = 0; k < 64; ++k) {
      float w = W1[u * 64 + k];
      a0  += h2f[r2 * 2 + 0][k] * w;
      a1f += h2f[r2 * 2 + 1][k] * w;
    }
    fc1s[r2 * 2 + 0][u] = fmaxf(a0, 0.f);
    fc1s[r2 * 2 + 1][u] = fmaxf(a1f, 0.f);
  }
  __syncthreads();
  // fc2: (8 x 128) @ (128 x 4) + b2
  if (tid < 32) {
    const int r = tid >> 2, cls = tid & 3;
    float a = b2[cls];
    for (int k = 0; k < 128; ++k) a += fc1s[r][k] * W2[cls * 128 + k];
    Out[(size_t)(r0 + r) * 4 + cls] = a;
  }
}

extern "C" void kernel_launch(void* const* d_in, const int* in_sizes, int n_in,
                              void* d_out, int out_size, void* d_ws, size_t ws_size,
                              hipStream_t stream) {
  const float* X    = (const float*)d_in[0];
  const float* Wp   = (const float*)d_in[1];
  const float* bp   = (const float*)d_in[2];
  const float* Wih1 = (const float*)d_in[3];
  const float* Whh1 = (const float*)d_in[4];
  const float* bih1 = (const float*)d_in[5];
  const float* bhh1 = (const float*)d_in[6];
  const float* Wih2 = (const float*)d_in[7];
  const float* Whh2 = (const float*)d_in[8];
  const float* bih2 = (const float*)d_in[9];
  const float* bhh2 = (const float*)d_in[10];
  const float* W1   = (const float*)d_in[11];
  const float* b1   = (const float*)d_in[12];
  const float* W2   = (const float*)d_in[13];
  const float* b2   = (const float*)d_in[14];
  float* Out = (float*)d_out;

  hipLaunchKernelGGL(lstm_fused, dim3(NBLK), dim3(NTHR), 0, stream,
                     X, Wp, bp, Wih1, Whh1, bih1, bhh1,
                     Wih2, Whh2, bih2, bhh2, W1, b1, W2, b2, Out);
}